// Round 1
// baseline (197.380 us; speedup 1.0000x reference)
//
#include <hip/hip_runtime.h>

// ---------------------------------------------------------------------------
// DigitConvolutionalModel: x(32768,784) -> conv3x3(valid) -> 676
//   -> relu(@W1(676,300)+b1) -> relu(@W2(300,300)+b2) -> @W3(300,10)+b3
//
// R7: kill the barrier/drain serialization (52 -> 17 barriers/block).
//  - B operands (W1f/W2f) are L2-resident (512KB/200KB): load per-wave
//    global->VGPR instead of LDS staging. No cross-wave load deps -> the
//    compiler pipelines with counted vmcnt; GEMM2/3 are barrier-free.
//  - wave remap: each wave owns 4 m-tiles x (3|2) n-tiles (waves 0-3: 3
//    tiles, 4-7: 2 tiles; per-SIMD balanced). B reused 4x in registers ->
//    ~0.7 MB L2 B-traffic per block (~360 MB total ~ 13 us, overlapped).
//  - LDS 58KB: Abuf (x band, 17KB) + hbuf (h1/h2, 40KB). 2 blocks/CU.
//  - prep_weights: 1 thread per bf16x8 group, coalesced 16B stores.
// ---------------------------------------------------------------------------

typedef __bf16 bf16_t;
typedef __bf16 bf16x4 __attribute__((ext_vector_type(4)));
typedef __bf16 bf16x8 __attribute__((ext_vector_type(8)));
typedef float  f32x4  __attribute__((ext_vector_type(4)));

#define MFMA16(a, b, c) __builtin_amdgcn_mfma_f32_16x16x32_bf16((a), (b), (c), 0, 0, 0)

#define W1F_ELEMS (25 * 20 * 64 * 8)  // 256000  (K=800, N=320)
#define W2F_ELEMS (10 * 20 * 64 * 8)  // 102400  (K=320, N=320)
#define W3F_ELEMS (10 * 1 * 64 * 8)   // 5120    (K=320, N=16)
#define ASTRIDE   136                 // bf16 row stride in Abuf (272B)

#define W1F_GRP 32000  // 25*20*64
#define W2F_GRP 12800  // 10*20*64
#define W3F_GRP 640    // 10*64

// ---------------------------------------------------------------------------
// One thread per output bf16x8 group (j=0..7 of the frag) -> coalesced 16B
// stores, W1 reads coalesced over nin. 45440 threads total.
// ---------------------------------------------------------------------------
__global__ __launch_bounds__(256) void prep_weights(
    const float* __restrict__ conv_w, const float* __restrict__ W1,
    const float* __restrict__ W2, const float* __restrict__ W3,
    bf16x8* __restrict__ W1f, bf16x8* __restrict__ W2f,
    bf16x8* __restrict__ W3f) {
    int idx = blockIdx.x * 256 + threadIdx.x;
    if (idx < W1F_GRP) {
        int within = idx & 63, quad = within >> 4, nin = within & 15;
        int t = idx >> 6;
        int nt = t % 20, kcv = t / 20;
        int kb = kcv * 32 + quad * 8, n = nt * 16 + nin;
        bf16x8 vec;
#pragma unroll
        for (int j = 0; j < 8; ++j) {
            int k = kb + j;
            float v = 0.0f;
            if (k < 784 && n < 300) {
                int py = k / 28, px = k - py * 28;
#pragma unroll
                for (int ky = 0; ky < 3; ++ky) {
                    int oy = py - ky;
                    if (oy < 0 || oy > 25) continue;
#pragma unroll
                    for (int kx = 0; kx < 3; ++kx) {
                        int ox = px - kx;
                        if (ox < 0 || ox > 25) continue;
                        v += conv_w[ky * 3 + kx] * W1[(oy * 26 + ox) * 300 + n];
                    }
                }
            }
            vec[j] = (bf16_t)v;
        }
        W1f[idx] = vec;
    } else if (idx < W1F_GRP + W2F_GRP) {
        int g = idx - W1F_GRP;
        int within = g & 63, quad = within >> 4, nin = within & 15;
        int t = g >> 6;
        int nt = t % 20, kcv = t / 20;
        int kb = kcv * 32 + quad * 8, n = nt * 16 + nin;
        bf16x8 vec;
#pragma unroll
        for (int j = 0; j < 8; ++j) {
            int k = kb + j;
            vec[j] = (bf16_t)((k < 300 && n < 300) ? W2[k * 300 + n] : 0.0f);
        }
        W2f[g] = vec;
    } else if (idx < W1F_GRP + W2F_GRP + W3F_GRP) {
        int g = idx - (W1F_GRP + W2F_GRP);
        int within = g & 63, quad = within >> 4, n = within & 15;
        int kcv = g >> 6, kb = kcv * 32 + quad * 8;
        bf16x8 vec;
#pragma unroll
        for (int j = 0; j < 8; ++j) {
            int k = kb + j;
            vec[j] = (bf16_t)((k < 300 && n < 10) ? W3[k * 10 + n] : 0.0f);
        }
        W3f[g] = vec;
    }
}

// ---------------------------------------------------------------------------
// Fused: out = relu(relu(x@W1eff+b1)@W2+b2)@W3+b3.
// Block = 64 rows, 512 thr (8 waves). Wave w: all 4 m-tiles, n-tiles
// [nt0, nt0+ntl) with ntl = 3 (w<4) or 2 (w>=4). B-frags straight from
// global (L2-hot). x staged per 128-col band in LDS (sequential-order map).
// ---------------------------------------------------------------------------
__global__ __launch_bounds__(512, 4) void fused_mlp(
    const float* __restrict__ x, const float* __restrict__ b1,
    const float* __restrict__ b2, const float* __restrict__ b3,
    const bf16x8* __restrict__ W1f, const bf16x8* __restrict__ W2f,
    const bf16x8* __restrict__ W3f, float* __restrict__ out) {
    __shared__ bf16_t Abuf[64 * ASTRIDE];  // 17.4 KB: one A band (64 x 128)
    __shared__ bf16x8 hbuf[40 * 64];       // 40 KB: h in A-frag order [10][4][64]

    const int tid = threadIdx.x;
    const int w   = tid >> 6;
    const int l   = tid & 63;
    const int q   = l >> 4;
    const int l15 = l & 15;
    const int r0  = blockIdx.x * 64;

    const bool t3   = (w < 4);
    const int  nt0  = t3 ? (w * 3) : (12 + (w - 4) * 2);
    const int  boff2 = t3 ? 128 : 64;  // 3rd-tile offset (dup of 2nd for 2-tile waves)

    // sequential-stage maps (bands 0-5): row = i*16 + (tid>>5), col4 = tid&31
    const int srow = tid >> 5;
    const int sc4  = tid & 31;
    // band-6 map: 64 rows x 8 float4 (first 4 valid)
    const int trow = tid >> 3;
    const int tc4  = tid & 7;

    float4 pf[4];
#pragma unroll
    for (int i = 0; i < 4; ++i)
        pf[i] = *(const float4*)(x + (size_t)(r0 + i * 16 + srow) * 784 + sc4 * 4);

    f32x4 acc[4][3];
#pragma unroll
    for (int m = 0; m < 4; ++m)
#pragma unroll
        for (int j = 0; j < 3; ++j) acc[m][j] = (f32x4){0.f, 0.f, 0.f, 0.f};

    const bf16x8* bB1 = W1f + nt0 * 64 + l;

    // ---------------- GEMM1 ------------------------------------------------
    int kc = 0;
    for (int band = 0; band < 7; ++band) {
        __syncthreads();  // prev band A-reads done

        if (band < 6) {
#pragma unroll
            for (int i = 0; i < 4; ++i) {
                bf16x4 v;
                v[0] = (bf16_t)pf[i].x; v[1] = (bf16_t)pf[i].y;
                v[2] = (bf16_t)pf[i].z; v[3] = (bf16_t)pf[i].w;
                *(bf16x4*)&Abuf[(i * 16 + srow) * ASTRIDE + sc4 * 4] = v;
            }
        } else {
            bf16x4 v;
            v[0] = (bf16_t)pf[0].x; v[1] = (bf16_t)pf[0].y;
            v[2] = (bf16_t)pf[0].z; v[3] = (bf16_t)pf[0].w;
            *(bf16x4*)&Abuf[trow * ASTRIDE + tc4 * 4] = v;
        }

        if (band + 1 < 6) {
#pragma unroll
            for (int i = 0; i < 4; ++i)
                pf[i] = *(const float4*)(x + (size_t)(r0 + i * 16 + srow) * 784 +
                                         (band + 1) * 128 + sc4 * 4);
        } else if (band + 1 == 6) {
            pf[0] = (tc4 < 4)
                ? *(const float4*)(x + (size_t)(r0 + trow) * 784 + 768 + tc4 * 4)
                : make_float4(0.f, 0.f, 0.f, 0.f);
        }

        __syncthreads();  // Abuf visible

#define G1CHUNK(KCL)                                                            \
        {                                                                       \
            bf16x8 a0 = *(const bf16x8*)&Abuf[( 0 + l15) * ASTRIDE + (KCL) * 32 + q * 8]; \
            bf16x8 a1 = *(const bf16x8*)&Abuf[(16 + l15) * ASTRIDE + (KCL) * 32 + q * 8]; \
            bf16x8 a2 = *(const bf16x8*)&Abuf[(32 + l15) * ASTRIDE + (KCL) * 32 + q * 8]; \
            bf16x8 a3 = *(const bf16x8*)&Abuf[(48 + l15) * ASTRIDE + (KCL) * 32 + q * 8]; \
            const bf16x8* bp = bB1 + kc * 1280;                                 \
            bf16x8 b0 = bp[0], b1v = bp[64], b2v = bp[boff2];                   \
            acc[0][0] = MFMA16(a0, b0, acc[0][0]);                              \
            acc[1][0] = MFMA16(a1, b0, acc[1][0]);                              \
            acc[2][0] = MFMA16(a2, b0, acc[2][0]);                              \
            acc[3][0] = MFMA16(a3, b0, acc[3][0]);                              \
            acc[0][1] = MFMA16(a0, b1v, acc[0][1]);                             \
            acc[1][1] = MFMA16(a1, b1v, acc[1][1]);                             \
            acc[2][1] = MFMA16(a2, b1v, acc[2][1]);                             \
            acc[3][1] = MFMA16(a3, b1v, acc[3][1]);                             \
            if (t3) {                                                           \
                acc[0][2] = MFMA16(a0, b2v, acc[0][2]);                         \
                acc[1][2] = MFMA16(a1, b2v, acc[1][2]);                         \
                acc[2][2] = MFMA16(a2, b2v, acc[2][2]);                         \
                acc[3][2] = MFMA16(a3, b2v, acc[3][2]);                         \
            }                                                                   \
            ++kc;                                                               \
        }

        if (band < 6) {
            G1CHUNK(0) G1CHUNK(1) G1CHUNK(2) G1CHUNK(3)
        } else {
            G1CHUNK(0)
        }
    }

    // ---------------- h1 = relu(C1+b1) -> hbuf (A-frag order) --------------
    bf16_t* hb = (bf16_t*)hbuf;

#define HSTORE(J, BIAS)                                                         \
    {                                                                           \
        int n = (nt0 + (J)) * 16 + l15;                                         \
        float bias = (n < 300) ? (BIAS)[n] : 0.0f;                              \
        int kh = n >> 5, quad = (n >> 3) & 3, jj = n & 7;                       \
        for (int mt = 0; mt < 4; ++mt)                                          \
            for (int r = 0; r < 4; ++r) {                                       \
                float v = acc[mt][(J)][r] + bias;                               \
                v = v > 0.f ? v : 0.f;                                          \
                hb[(((kh * 4 + mt) * 64 + quad * 16 + q * 4 + r) << 3) + jj] =  \
                    (bf16_t)v;                                                  \
            }                                                                   \
    }

    HSTORE(0, b1)
    HSTORE(1, b1)
    if (t3) HSTORE(2, b1)
    __syncthreads();  // h1 visible

    // ---------------- GEMM2: barrier-free; W2f frags from global (L2) ------
#pragma unroll
    for (int m = 0; m < 4; ++m)
#pragma unroll
        for (int j = 0; j < 3; ++j) acc[m][j] = (f32x4){0.f, 0.f, 0.f, 0.f};

    const bf16x8* bB2 = W2f + nt0 * 64 + l;

#define G2CHUNK(KC2)                                                            \
    {                                                                           \
        bf16x8 a0 = hbuf[((KC2) * 4 + 0) * 64 + l];                             \
        bf16x8 a1 = hbuf[((KC2) * 4 + 1) * 64 + l];                             \
        bf16x8 a2 = hbuf[((KC2) * 4 + 2) * 64 + l];                             \
        bf16x8 a3 = hbuf[((KC2) * 4 + 3) * 64 + l];                             \
        const bf16x8* bp = bB2 + (KC2) * 1280;                                  \
        bf16x8 b0 = bp[0], b1v = bp[64], b2v = bp[boff2];                       \
        acc[0][0] = MFMA16(a0, b0, acc[0][0]);                                  \
        acc[1][0] = MFMA16(a1, b0, acc[1][0]);                                  \
        acc[2][0] = MFMA16(a2, b0, acc[2][0]);                                  \
        acc[3][0] = MFMA16(a3, b0, acc[3][0]);                                  \
        acc[0][1] = MFMA16(a0, b1v, acc[0][1]);                                 \
        acc[1][1] = MFMA16(a1, b1v, acc[1][1]);                                 \
        acc[2][1] = MFMA16(a2, b1v, acc[2][1]);                                 \
        acc[3][1] = MFMA16(a3, b1v, acc[3][1]);                                 \
        if (t3) {                                                               \
            acc[0][2] = MFMA16(a0, b2v, acc[0][2]);                             \
            acc[1][2] = MFMA16(a1, b2v, acc[1][2]);                             \
            acc[2][2] = MFMA16(a2, b2v, acc[2][2]);                             \
            acc[3][2] = MFMA16(a3, b2v, acc[3][2]);                             \
        }                                                                       \
    }

    G2CHUNK(0) G2CHUNK(1) G2CHUNK(2) G2CHUNK(3) G2CHUNK(4)
    G2CHUNK(5) G2CHUNK(6) G2CHUNK(7) G2CHUNK(8) G2CHUNK(9)

    __syncthreads();  // all hbuf(h1) reads done before h2 overwrite

    // ---------------- h2 = relu(C2+b2) -> hbuf -----------------------------
    HSTORE(0, b2)
    HSTORE(1, b2)
    if (t3) HSTORE(2, b2)
    __syncthreads();  // h2 visible

    // ---------------- GEMM3: waves 0-3 (mt=w); W3f frags from global -------
    if (w < 4) {
        f32x4 acc3 = (f32x4){0.f, 0.f, 0.f, 0.f};
#pragma unroll
        for (int kc3 = 0; kc3 < 10; ++kc3)
            acc3 = MFMA16(hbuf[(kc3 * 4 + w) * 64 + l], W3f[kc3 * 64 + l], acc3);
        if (l15 < 10) {
            float bias = b3[l15];
#pragma unroll
            for (int r = 0; r < 4; ++r)
                out[(size_t)(r0 + w * 16 + q * 4 + r) * 10 + l15] = acc3[r] + bias;
        }
    }
}

// ---------------------------------------------------------------------------
extern "C" void kernel_launch(void* const* d_in, const int* in_sizes, int n_in,
                              void* d_out, int out_size, void* d_ws, size_t ws_size,
                              hipStream_t stream) {
    const float* x      = (const float*)d_in[0];
    const float* conv_w = (const float*)d_in[1];
    const float* W1     = (const float*)d_in[2];
    const float* b1     = (const float*)d_in[3];
    const float* W2     = (const float*)d_in[4];
    const float* b2     = (const float*)d_in[5];
    const float* W3     = (const float*)d_in[6];
    const float* b3     = (const float*)d_in[7];
    float* out = (float*)d_out;

    char* ws = (char*)d_ws;
    bf16_t* W1f = (bf16_t*)(ws);
    bf16_t* W2f = (bf16_t*)(ws + (size_t)W1F_ELEMS * 2);
    bf16_t* W3f = (bf16_t*)(ws + (size_t)(W1F_ELEMS + W2F_ELEMS) * 2);
    if (ws_size < (size_t)(W1F_ELEMS + W2F_ELEMS + W3F_ELEMS) * 2) return;

    int prep_total = W1F_GRP + W2F_GRP + W3F_GRP;  // 45440 threads
    prep_weights<<<(prep_total + 255) / 256, 256, 0, stream>>>(
        conv_w, W1, W2, W3, (bf16x8*)W1f, (bf16x8*)W2f, (bf16x8*)W3f);

    fused_mlp<<<32768 / 64, 512, 0, stream>>>(
        x, b1, b2, b3, (const bf16x8*)W1f, (const bf16x8*)W2f,
        (const bf16x8*)W3f, out);
}

// Round 2
// 194.658 us; speedup vs baseline: 1.0140x; 1.0140x over previous
//
#include <hip/hip_runtime.h>

// ---------------------------------------------------------------------------
// DigitConvolutionalModel: x(32768,784) -> conv3x3(valid) -> 676
//   -> relu(@W1(676,300)+b1) -> relu(@W2(300,300)+b2) -> @W3(300,10)+b3
//
// R8: make the x prefetch REAL (R6/R7 both drained it at every barrier).
//  - Band loop uses ONE raw s_barrier per band (no vmcnt drain): inline-asm
//    s_waitcnt lgkmcnt(0) + __builtin_amdgcn_s_barrier + sched_barrier(0).
//    pf global loads stay in flight across the barrier; backend emits
//    counted vmcnt for B-frag uses (pf issued first in program order).
//  - Abuf double-buffered (2 x 17.4KB): write band b into buf[b&1] while
//    other waves still compute band b-1 from buf[(b-1)&1]. 7 barriers total
//    in GEMM1; tail keeps 3 real __syncthreads (h1/h2 hand-offs).
//  - B operands per-wave from L2 (R7); wave = 4 m-tiles x (3|2) n-tiles.
//  - LDS 75KB: Abuf dbuf 35KB + hbuf 40KB. 2 blocks/CU.
// ---------------------------------------------------------------------------

typedef __bf16 bf16_t;
typedef __bf16 bf16x4 __attribute__((ext_vector_type(4)));
typedef __bf16 bf16x8 __attribute__((ext_vector_type(8)));
typedef float  f32x4  __attribute__((ext_vector_type(4)));

#define MFMA16(a, b, c) __builtin_amdgcn_mfma_f32_16x16x32_bf16((a), (b), (c), 0, 0, 0)

#define W1F_ELEMS (25 * 20 * 64 * 8)  // 256000  (K=800, N=320)
#define W2F_ELEMS (10 * 20 * 64 * 8)  // 102400  (K=320, N=320)
#define W3F_ELEMS (10 * 1 * 64 * 8)   // 5120    (K=320, N=16)
#define ASTRIDE   136                 // bf16 row stride in Abuf (272B)

#define W1F_GRP 32000  // 25*20*64
#define W2F_GRP 12800  // 10*20*64
#define W3F_GRP 640    // 10*64

// Raw workgroup barrier WITHOUT vmcnt drain: waits only this wave's LDS ops
// (ds_write commit / ds_read done), then s_barrier. sched_barrier keeps the
// compiler from hoisting dependent ops above the wait (guide rule #18).
#define WG_BARRIER_NODRAIN()                                   \
    do {                                                       \
        asm volatile("s_waitcnt lgkmcnt(0)" ::: "memory");     \
        __builtin_amdgcn_s_barrier();                          \
        __builtin_amdgcn_sched_barrier(0);                     \
    } while (0)

// ---------------------------------------------------------------------------
// One thread per output bf16x8 group -> coalesced 16B stores.
// ---------------------------------------------------------------------------
__global__ __launch_bounds__(256) void prep_weights(
    const float* __restrict__ conv_w, const float* __restrict__ W1,
    const float* __restrict__ W2, const float* __restrict__ W3,
    bf16x8* __restrict__ W1f, bf16x8* __restrict__ W2f,
    bf16x8* __restrict__ W3f) {
    int idx = blockIdx.x * 256 + threadIdx.x;
    if (idx < W1F_GRP) {
        int within = idx & 63, quad = within >> 4, nin = within & 15;
        int t = idx >> 6;
        int nt = t % 20, kcv = t / 20;
        int kb = kcv * 32 + quad * 8, n = nt * 16 + nin;
        bf16x8 vec;
#pragma unroll
        for (int j = 0; j < 8; ++j) {
            int k = kb + j;
            float v = 0.0f;
            if (k < 784 && n < 300) {
                int py = k / 28, px = k - py * 28;
#pragma unroll
                for (int ky = 0; ky < 3; ++ky) {
                    int oy = py - ky;
                    if (oy < 0 || oy > 25) continue;
#pragma unroll
                    for (int kx = 0; kx < 3; ++kx) {
                        int ox = px - kx;
                        if (ox < 0 || ox > 25) continue;
                        v += conv_w[ky * 3 + kx] * W1[(oy * 26 + ox) * 300 + n];
                    }
                }
            }
            vec[j] = (bf16_t)v;
        }
        W1f[idx] = vec;
    } else if (idx < W1F_GRP + W2F_GRP) {
        int g = idx - W1F_GRP;
        int within = g & 63, quad = within >> 4, nin = within & 15;
        int t = g >> 6;
        int nt = t % 20, kcv = t / 20;
        int kb = kcv * 32 + quad * 8, n = nt * 16 + nin;
        bf16x8 vec;
#pragma unroll
        for (int j = 0; j < 8; ++j) {
            int k = kb + j;
            vec[j] = (bf16_t)((k < 300 && n < 300) ? W2[k * 300 + n] : 0.0f);
        }
        W2f[g] = vec;
    } else if (idx < W1F_GRP + W2F_GRP + W3F_GRP) {
        int g = idx - (W1F_GRP + W2F_GRP);
        int within = g & 63, quad = within >> 4, n = within & 15;
        int kcv = g >> 6, kb = kcv * 32 + quad * 8;
        bf16x8 vec;
#pragma unroll
        for (int j = 0; j < 8; ++j) {
            int k = kb + j;
            vec[j] = (bf16_t)((k < 300 && n < 10) ? W3[k * 10 + n] : 0.0f);
        }
        W3f[g] = vec;
    }
}

// ---------------------------------------------------------------------------
// Fused: out = relu(relu(x@W1eff+b1)@W2+b2)@W3+b3.
// Block = 64 rows, 512 thr (8 waves). Wave w: 4 m-tiles x (3|2) n-tiles.
// ---------------------------------------------------------------------------
__global__ __launch_bounds__(512, 4) void fused_mlp(
    const float* __restrict__ x, const float* __restrict__ b1,
    const float* __restrict__ b2, const float* __restrict__ b3,
    const bf16x8* __restrict__ W1f, const bf16x8* __restrict__ W2f,
    const bf16x8* __restrict__ W3f, float* __restrict__ out) {
    __shared__ bf16_t Abuf[2][64 * ASTRIDE];  // 35 KB: x band ring-2
    __shared__ bf16x8 hbuf[40 * 64];          // 40 KB: h in A-frag order

    const int tid = threadIdx.x;
    const int w   = tid >> 6;
    const int l   = tid & 63;
    const int q   = l >> 4;
    const int l15 = l & 15;
    const int r0  = blockIdx.x * 64;

    const bool t3    = (w < 4);
    const int  nt0   = t3 ? (w * 3) : (12 + (w - 4) * 2);
    const int  boff2 = t3 ? 128 : 64;  // 3rd-tile offset (dup of 2nd if 2-tile)

    // sequential-stage maps (bands 0-5): row = i*16 + (tid>>5), col4 = tid&31
    const int srow = tid >> 5;
    const int sc4  = tid & 31;
    // band-6 map: 64 rows x 8 float4 (first 4 valid)
    const int trow = tid >> 3;
    const int tc4  = tid & 7;

    float4 pf[4];
#pragma unroll
    for (int i = 0; i < 4; ++i)
        pf[i] = *(const float4*)(x + (size_t)(r0 + i * 16 + srow) * 784 + sc4 * 4);

    f32x4 acc[4][3];
#pragma unroll
    for (int m = 0; m < 4; ++m)
#pragma unroll
        for (int j = 0; j < 3; ++j) acc[m][j] = (f32x4){0.f, 0.f, 0.f, 0.f};

    const bf16x8* bB1 = W1f + nt0 * 64 + l;

    // ---------------- GEMM1: 1 raw barrier per band, pf stays in flight ----
    int kc = 0;
    for (int band = 0; band < 7; ++band) {
        bf16_t* ab = Abuf[band & 1];

        // stage band b into buf[b&1] (cvt waits pf via compiler vmcnt)
        if (band < 6) {
#pragma unroll
            for (int i = 0; i < 4; ++i) {
                bf16x4 v;
                v[0] = (bf16_t)pf[i].x; v[1] = (bf16_t)pf[i].y;
                v[2] = (bf16_t)pf[i].z; v[3] = (bf16_t)pf[i].w;
                *(bf16x4*)&ab[(i * 16 + srow) * ASTRIDE + sc4 * 4] = v;
            }
        } else {
            bf16x4 v;
            v[0] = (bf16_t)pf[0].x; v[1] = (bf16_t)pf[0].y;
            v[2] = (bf16_t)pf[0].z; v[3] = (bf16_t)pf[0].w;
            *(bf16x4*)&ab[trow * ASTRIDE + tc4 * 4] = v;
        }

        // issue next band's pf: crosses ONLY raw barriers -> stays in flight
        if (band + 1 < 6) {
#pragma unroll
            for (int i = 0; i < 4; ++i)
                pf[i] = *(const float4*)(x + (size_t)(r0 + i * 16 + srow) * 784 +
                                         (band + 1) * 128 + sc4 * 4);
        } else if (band + 1 == 6) {
            pf[0] = (tc4 < 4)
                ? *(const float4*)(x + (size_t)(r0 + trow) * 784 + 768 + tc4 * 4)
                : make_float4(0.f, 0.f, 0.f, 0.f);
        }

        WG_BARRIER_NODRAIN();  // own ds_writes committed; no vmcnt drain

#define G1CHUNK(KCL)                                                            \
        {                                                                       \
            bf16x8 a0 = *(const bf16x8*)&ab[( 0 + l15) * ASTRIDE + (KCL) * 32 + q * 8]; \
            bf16x8 a1 = *(const bf16x8*)&ab[(16 + l15) * ASTRIDE + (KCL) * 32 + q * 8]; \
            bf16x8 a2 = *(const bf16x8*)&ab[(32 + l15) * ASTRIDE + (KCL) * 32 + q * 8]; \
            bf16x8 a3 = *(const bf16x8*)&ab[(48 + l15) * ASTRIDE + (KCL) * 32 + q * 8]; \
            const bf16x8* bp = bB1 + kc * 1280;                                 \
            bf16x8 b0 = bp[0], b1v = bp[64], b2v = bp[boff2];                   \
            acc[0][0] = MFMA16(a0, b0, acc[0][0]);                              \
            acc[1][0] = MFMA16(a1, b0, acc[1][0]);                              \
            acc[2][0] = MFMA16(a2, b0, acc[2][0]);                              \
            acc[3][0] = MFMA16(a3, b0, acc[3][0]);                              \
            acc[0][1] = MFMA16(a0, b1v, acc[0][1]);                             \
            acc[1][1] = MFMA16(a1, b1v, acc[1][1]);                             \
            acc[2][1] = MFMA16(a2, b1v, acc[2][1]);                             \
            acc[3][1] = MFMA16(a3, b1v, acc[3][1]);                             \
            if (t3) {                                                           \
                acc[0][2] = MFMA16(a0, b2v, acc[0][2]);                         \
                acc[1][2] = MFMA16(a1, b2v, acc[1][2]);                         \
                acc[2][2] = MFMA16(a2, b2v, acc[2][2]);                         \
                acc[3][2] = MFMA16(a3, b2v, acc[3][2]);                         \
            }                                                                   \
            ++kc;                                                               \
        }

        if (band < 6) {
            G1CHUNK(0) G1CHUNK(1) G1CHUNK(2) G1CHUNK(3)
        } else {
            G1CHUNK(0)
        }
    }

    // ---------------- h1 = relu(C1+b1) -> hbuf (A-frag order) --------------
    bf16_t* hb = (bf16_t*)hbuf;

#define HSTORE(J, BIAS)                                                         \
    {                                                                           \
        int n = (nt0 + (J)) * 16 + l15;                                         \
        float bias = (n < 300) ? (BIAS)[n] : 0.0f;                              \
        int kh = n >> 5, quad = (n >> 3) & 3, jj = n & 7;                       \
        for (int mt = 0; mt < 4; ++mt)                                          \
            for (int r = 0; r < 4; ++r) {                                       \
                float v = acc[mt][(J)][r] + bias;                               \
                v = v > 0.f ? v : 0.f;                                          \
                hb[(((kh * 4 + mt) * 64 + quad * 16 + q * 4 + r) << 3) + jj] =  \
                    (bf16_t)v;                                                  \
            }                                                                   \
    }

    HSTORE(0, b1)
    HSTORE(1, b1)
    if (t3) HSTORE(2, b1)
    __syncthreads();  // h1 visible (full drain OK: pf all consumed)

    // ---------------- GEMM2: barrier-free; W2f frags from global (L2) ------
#pragma unroll
    for (int m = 0; m < 4; ++m)
#pragma unroll
        for (int j = 0; j < 3; ++j) acc[m][j] = (f32x4){0.f, 0.f, 0.f, 0.f};

    const bf16x8* bB2 = W2f + nt0 * 64 + l;

#define G2CHUNK(KC2)                                                            \
    {                                                                           \
        bf16x8 a0 = hbuf[((KC2) * 4 + 0) * 64 + l];                             \
        bf16x8 a1 = hbuf[((KC2) * 4 + 1) * 64 + l];                             \
        bf16x8 a2 = hbuf[((KC2) * 4 + 2) * 64 + l];                             \
        bf16x8 a3 = hbuf[((KC2) * 4 + 3) * 64 + l];                             \
        const bf16x8* bp = bB2 + (KC2) * 1280;                                  \
        bf16x8 b0 = bp[0], b1v = bp[64], b2v = bp[boff2];                       \
        acc[0][0] = MFMA16(a0, b0, acc[0][0]);                                  \
        acc[1][0] = MFMA16(a1, b0, acc[1][0]);                                  \
        acc[2][0] = MFMA16(a2, b0, acc[2][0]);                                  \
        acc[3][0] = MFMA16(a3, b0, acc[3][0]);                                  \
        acc[0][1] = MFMA16(a0, b1v, acc[0][1]);                                 \
        acc[1][1] = MFMA16(a1, b1v, acc[1][1]);                                 \
        acc[2][1] = MFMA16(a2, b1v, acc[2][1]);                                 \
        acc[3][1] = MFMA16(a3, b1v, acc[3][1]);                                 \
        if (t3) {                                                               \
            acc[0][2] = MFMA16(a0, b2v, acc[0][2]);                             \
            acc[1][2] = MFMA16(a1, b2v, acc[1][2]);                             \
            acc[2][2] = MFMA16(a2, b2v, acc[2][2]);                             \
            acc[3][2] = MFMA16(a3, b2v, acc[3][2]);                             \
        }                                                                       \
    }

    G2CHUNK(0) G2CHUNK(1) G2CHUNK(2) G2CHUNK(3) G2CHUNK(4)
    G2CHUNK(5) G2CHUNK(6) G2CHUNK(7) G2CHUNK(8) G2CHUNK(9)

    __syncthreads();  // all hbuf(h1) reads done before h2 overwrite

    // ---------------- h2 = relu(C2+b2) -> hbuf -----------------------------
    HSTORE(0, b2)
    HSTORE(1, b2)
    if (t3) HSTORE(2, b2)
    __syncthreads();  // h2 visible

    // ---------------- GEMM3: waves 0-3 (mt=w); W3f frags from global -------
    if (w < 4) {
        f32x4 acc3 = (f32x4){0.f, 0.f, 0.f, 0.f};
#pragma unroll
        for (int kc3 = 0; kc3 < 10; ++kc3)
            acc3 = MFMA16(hbuf[(kc3 * 4 + w) * 64 + l], W3f[kc3 * 64 + l], acc3);
        if (l15 < 10) {
            float bias = b3[l15];
#pragma unroll
            for (int r = 0; r < 4; ++r)
                out[(size_t)(r0 + w * 16 + q * 4 + r) * 10 + l15] = acc3[r] + bias;
        }
    }
}

// ---------------------------------------------------------------------------
extern "C" void kernel_launch(void* const* d_in, const int* in_sizes, int n_in,
                              void* d_out, int out_size, void* d_ws, size_t ws_size,
                              hipStream_t stream) {
    const float* x      = (const float*)d_in[0];
    const float* conv_w = (const float*)d_in[1];
    const float* W1     = (const float*)d_in[2];
    const float* b1     = (const float*)d_in[3];
    const float* W2     = (const float*)d_in[4];
    const float* b2     = (const float*)d_in[5];
    const float* W3     = (const float*)d_in[6];
    const float* b3     = (const float*)d_in[7];
    float* out = (float*)d_out;

    char* ws = (char*)d_ws;
    bf16_t* W1f = (bf16_t*)(ws);
    bf16_t* W2f = (bf16_t*)(ws + (size_t)W1F_ELEMS * 2);
    bf16_t* W3f = (bf16_t*)(ws + (size_t)(W1F_ELEMS + W2F_ELEMS) * 2);
    if (ws_size < (size_t)(W1F_ELEMS + W2F_ELEMS + W3F_ELEMS) * 2) return;

    int prep_total = W1F_GRP + W2F_GRP + W3F_GRP;  // 45440 threads
    prep_weights<<<(prep_total + 255) / 256, 256, 0, stream>>>(
        conv_w, W1, W2, W3, (bf16x8*)W1f, (bf16x8*)W2f, (bf16x8*)W3f);

    fused_mlp<<<32768 / 64, 512, 0, stream>>>(
        x, b1, b2, b3, (const bf16x8*)W1f, (const bf16x8*)W2f,
        (const bf16x8*)W3f, out);
}